// Round 5
// baseline (1153.069 us; speedup 1.0000x reference)
//
#include <hip/hip_runtime.h>

typedef _Float16 f16;
typedef _Float16 f16x4_t __attribute__((ext_vector_type(4)));
typedef _Float16 f16x8_t __attribute__((ext_vector_type(8)));
typedef float    f32x4_t __attribute__((ext_vector_type(4)));

#define HD 512          // h
#define CD 256          // c
#define ND 512          // N (codebook)
#define MROWS (4*24*2048)
#define BM 32
#define NTHR 512
#define TINV 10.0f      // 1/TEMP

// ---------------- prep: M = Wp(512x256) @ Wq(256x512) -> fp16 [512][512]; sb[n] = sum_c b[c]*Wp[n][c]
__global__ void prep_M(const float* __restrict__ Wp, const float* __restrict__ Wq,
                       const float* __restrict__ bq, f16* __restrict__ Mt,
                       float* __restrict__ sb) {
  const int n = blockIdx.x;   // 0..511
  const int t = threadIdx.x;  // 0..255
  __shared__ float wpr[CD];
  __shared__ float sred[CD];
  wpr[t] = Wp[n * CD + t];
  __syncthreads();
  float a0 = 0.f, a1 = 0.f;
  #pragma unroll 8
  for (int c = 0; c < CD; ++c) {
    const float w = wpr[c];
    a0 = fmaf(w, Wq[c * HD + t], a0);
    a1 = fmaf(w, Wq[c * HD + t + 256], a1);
  }
  Mt[n * HD + t] = (f16)a0;
  Mt[n * HD + t + 256] = (f16)a1;
  sred[t] = wpr[t] * bq[t];
  __syncthreads();
  for (int s = 128; s > 0; s >>= 1) {
    if (t < s) sred[t] += sred[t + s];
    __syncthreads();
  }
  if (t == 0) sb[n] = sred[0];
}

// ---------------- prep: WpT fp16 [256][512], WpT[c][n] = Wp[n][c]
__global__ void prep_WpT(const float* __restrict__ Wp, f16* __restrict__ WpT) {
  const int c = blockIdx.x;   // 0..255
  const int n = threadIdx.x;  // 0..511
  WpT[c * ND + n] = (f16)Wp[n * CD + c];
}

// ---------------- fused main: scores = H@Mt^T (+sb), direct-exp softmax, Q out, P = Q@Wp
// Register model (R1-R3 measured): __launch_bounds__ 2nd arg = min waves/EU;
// TOTAL reg budget (VGPR+AGPR, unified file) = 512/waves_per_EU.
// (512,4) -> 128 total/wave -> 4 waves/EU -> 2 WGs/CU. BM=32 keeps live state ~100 regs.
// SWIZZLE RULE (R4 lesson): XOR must be applied to the FULL byte offset (XOR-last).
// Hoisting it before adding ks*64 carries into bit 7 instead of toggling bit 6.
__global__ __launch_bounds__(NTHR, 4)
void fused_main(const float* __restrict__ Hl, const f16* __restrict__ Mt,
                const f16* __restrict__ WpT, const float* __restrict__ sb,
                float* __restrict__ outP, float* __restrict__ outQ) {
  // 32 KiB buffer: holds H fp16 -> Q fp16 -> P fp32 (XOR-swizzled rows, stride 1024B)
  __shared__ __align__(16) char AQraw[BM * HD * 2];
  __shared__ float red[BM][4];
  __shared__ float rstat[BM];

  const int tid  = threadIdx.x;
  const int lane = tid & 63;
  const int wid  = tid >> 6;         // 0..7
  const int wr   = wid >> 2;         // 0..1 (row half: 16 rows)
  const int wc   = wid & 3;          // 0..3 (col quarter)
  const int q4   = lane >> 4;        // 0..3
  const int l16  = lane & 15;
  const long rowbase = (long)blockIdx.x * BM;

  // ---- stage H: 32 rows x 512 fp32 -> fp16 LDS (swizzled) ----
  {
    const float4* __restrict__ src = (const float4*)(Hl + rowbase * HD);
    #pragma unroll
    for (int it = 0; it < (BM * HD / 4) / NTHR; ++it) {   // 8 iters
      const int f = it * NTHR + tid;                      // float4 index
      const float4 v = src[f];
      const int row = f >> 7;                             // 128 chunks per row
      int byteoff = row * (HD * 2) + ((f & 127) << 3);
      byteoff ^= (row & 7) << 4;
      f16x4_t h;
      h[0] = (f16)v.x; h[1] = (f16)v.y; h[2] = (f16)v.z; h[3] = (f16)v.w;
      *(f16x4_t*)(AQraw + byteoff) = h;
    }
  }
  __syncthreads();

  // ---- GEMM1: scores[32][512] = H_f16 @ Mt^T, fp32 acc ----
  f32x4_t acc[8];
  #pragma unroll
  for (int j = 0; j < 8; ++j)
    #pragma unroll
    for (int k = 0; k < 4; ++k) acc[j][k] = 0.f;

  {
    const f16* __restrict__ mb = Mt + (long)(wc * 128 + l16) * HD + q4 * 8;
    const int arow = wr * 16 + l16;
    for (int ks = 0; ks < 16; ++ks) {
      int byteoff = arow * (HD * 2) + ks * 64 + q4 * 16;
      byteoff ^= (arow & 7) << 4;                          // XOR-last!
      const f16x8_t a = *(const f16x8_t*)(AQraw + byteoff);
      #pragma unroll
      for (int nf = 0; nf < 8; ++nf) {
        const f16x8_t b = *(const f16x8_t*)(mb + nf * 16 * HD + ks * 32);
        acc[nf] = __builtin_amdgcn_mfma_f32_16x16x32_f16(a, b, acc[nf], 0, 0, 0);
      }
    }
  }

  // ---- softmax over N=512, direct exp (no max pass: |logit| <~ 54 << 88) ----
  // thread holds rows rloc = wr*16 + q4*4 + r, cols wc*128 + nf*16 + l16
  float sb10[8];
  #pragma unroll
  for (int nf = 0; nf < 8; ++nf) sb10[nf] = sb[wc * 128 + nf * 16 + l16] * TINV;

  float ps[4] = {0.f, 0.f, 0.f, 0.f};
  #pragma unroll
  for (int nf = 0; nf < 8; ++nf)
    #pragma unroll
    for (int r = 0; r < 4; ++r) {
      const float e = __expf(fmaf(acc[nf][r], TINV, sb10[nf]));
      acc[nf][r] = e;
      ps[r] += e;
    }
  #pragma unroll
  for (int st = 8; st >= 1; st >>= 1)
    #pragma unroll
    for (int r = 0; r < 4; ++r)
      ps[r] += __shfl_xor(ps[r], st, 64);

  if (l16 == 0) {
    #pragma unroll
    for (int r = 0; r < 4; ++r)
      red[wr * 16 + q4 * 4 + r][wc] = ps[r];
  }
  __syncthreads();
  if (tid < BM)
    rstat[tid] = 1.0f / (red[tid][0] + red[tid][1] + red[tid][2] + red[tid][3]);
  __syncthreads();

  float rinv[4];
  #pragma unroll
  for (int r = 0; r < 4; ++r)
    rinv[r] = rstat[wr * 16 + q4 * 4 + r];

  // ---- Q fp16 into AQ (H fully consumed) ----
  #pragma unroll
  for (int nf = 0; nf < 8; ++nf)
    #pragma unroll
    for (int r = 0; r < 4; ++r) {
      const int rloc = wr * 16 + q4 * 4 + r;
      const int col  = wc * 128 + nf * 16 + l16;
      const float q = acc[nf][r] * rinv[r];
      int byteoff = rloc * (ND * 2) + col * 2;
      byteoff ^= (rloc & 7) << 4;
      *(f16*)(AQraw + byteoff) = (f16)q;
    }
  __syncthreads();

  // ---- Q global store: coalesced float4 from LDS ----
  {
    #pragma unroll
    for (int it = 0; it < (BM * ND / 4) / NTHR; ++it) {   // 8 iters
      const int f = it * NTHR + tid;                      // f16x4 chunk index
      const int row = f >> 7;                             // 128 chunks per row
      int byteoff = row * (ND * 2) + ((f & 127) << 3);
      byteoff ^= (row & 7) << 4;
      const f16x4_t qv = *(const f16x4_t*)(AQraw + byteoff);
      float4 o;
      o.x = (float)qv[0]; o.y = (float)qv[1]; o.z = (float)qv[2]; o.w = (float)qv[3];
      *(float4*)(outQ + (rowbase + row) * ND + ((f & 127) << 2)) = o;
    }
  }

  // ---- GEMM3: P[32][256] = Q_f16 @ Wp  (B = WpT[c][n]) ----
  f32x4_t acc2[4];
  #pragma unroll
  for (int j = 0; j < 4; ++j)
    #pragma unroll
    for (int k = 0; k < 4; ++k) acc2[j][k] = 0.f;

  {
    const f16* __restrict__ wb = WpT + (long)(wc * 64 + l16) * ND + q4 * 8;
    const int arow = wr * 16 + l16;
    for (int ks = 0; ks < 16; ++ks) {
      int byteoff = arow * (ND * 2) + ks * 64 + q4 * 16;
      byteoff ^= (arow & 7) << 4;                          // XOR-last!
      const f16x8_t a = *(const f16x8_t*)(AQraw + byteoff);
      #pragma unroll
      for (int nf = 0; nf < 4; ++nf) {
        const f16x8_t b = *(const f16x8_t*)(wb + nf * 16 * ND + ks * 32);
        acc2[nf] = __builtin_amdgcn_mfma_f32_16x16x32_f16(a, b, acc2[nf], 0, 0, 0);
      }
    }
  }
  __syncthreads();   // everyone done reading Q from AQ before overwriting with P

  // ---- P fp32 scatter into AQ, then coalesced store ----
  {
    #pragma unroll
    for (int nf = 0; nf < 4; ++nf)
      #pragma unroll
      for (int r = 0; r < 4; ++r) {
        const int rloc = wr * 16 + q4 * 4 + r;
        const int col  = wc * 64 + nf * 16 + l16;
        int byteoff = rloc * (CD * 4) + col * 4;
        byteoff ^= (rloc & 7) << 4;
        *(float*)(AQraw + byteoff) = acc2[nf][r];
      }
    __syncthreads();
    #pragma unroll
    for (int it = 0; it < (BM * CD / 4) / NTHR; ++it) {   // 4 iters
      const int f = it * NTHR + tid;                      // float4 chunk index
      const int row = f >> 6;                             // 64 chunks per row
      int byteoff = row * (CD * 4) + ((f & 63) << 4);
      byteoff ^= (row & 7) << 4;
      const float4 pv = *(const float4*)(AQraw + byteoff);
      *(float4*)(outP + (rowbase + row) * CD + ((f & 63) << 2)) = pv;
    }
  }
}

extern "C" void kernel_launch(void* const* d_in, const int* in_sizes, int n_in,
                              void* d_out, int out_size, void* d_ws, size_t ws_size,
                              hipStream_t stream) {
  const float* Hl = (const float*)d_in[0];   // (B,T,V,H)
  const float* Wp = (const float*)d_in[1];   // (N,C)
  const float* Wq = (const float*)d_in[2];   // (C,H)
  const float* bq = (const float*)d_in[3];   // (C,)

  float* outP = (float*)d_out;                         // (M, C)
  float* outQ = (float*)d_out + (long)MROWS * CD;      // (M, N)

  f16*   Mt  = (f16*)d_ws;                                        // 512*512*2 = 512 KiB
  f16*   WpT = (f16*)((char*)d_ws + ND * HD * 2);                 // 256*512*2 = 256 KiB
  float* sb  = (float*)((char*)d_ws + ND * HD * 2 + CD * ND * 2); // 2 KiB

  prep_M  <<<ND, CD, 0, stream>>>(Wp, Wq, bq, Mt, sb);
  prep_WpT<<<CD, ND, 0, stream>>>(Wp, WpT);
  fused_main<<<MROWS / BM, NTHR, 0, stream>>>(Hl, Mt, WpT, sb, outP, outQ);
}

// Round 6
// 527.775 us; speedup vs baseline: 2.1848x; 2.1848x over previous
//
#include <hip/hip_runtime.h>

typedef _Float16 f16;
typedef _Float16 f16x4_t __attribute__((ext_vector_type(4)));
typedef _Float16 f16x8_t __attribute__((ext_vector_type(8)));
typedef float    f32x4_t __attribute__((ext_vector_type(4)));

#define HD 512          // h
#define CD 256          // c
#define ND 512          // N (codebook)
#define MROWS (4*24*2048)
#define BM 64
#define NTHR 512
#define TINV 10.0f      // 1/TEMP

// Fragment layout for MFMA B operands: for (tile t over 16 cols, ks over K/32):
// 64 lanes x 16B contiguous. Element (n,h) -> ((((n>>4)*16+(h>>5))*4+((h>>3)&3))*16+(n&15))*8+(h&7)
__device__ __forceinline__ int fragoff(int n, int h, int ntiles_times) {
  return ((((n >> 4) * 16 + (h >> 5)) * 4 + ((h >> 3) & 3)) * 16 + (n & 15)) * 8 + (h & 7);
}

// ---------------- prep: M = Wp(512x256) @ Wq(256x512) -> fp16 fragment layout; sb[n] = sum_c b[c]*Wp[n][c]
__global__ void prep_M(const float* __restrict__ Wp, const float* __restrict__ Wq,
                       const float* __restrict__ bq, f16* __restrict__ MtF,
                       float* __restrict__ sb) {
  const int n = blockIdx.x;   // 0..511
  const int t = threadIdx.x;  // 0..255
  __shared__ float wpr[CD];
  __shared__ float sred[CD];
  wpr[t] = Wp[n * CD + t];
  __syncthreads();
  float a0 = 0.f, a1 = 0.f;
  #pragma unroll 8
  for (int c = 0; c < CD; ++c) {
    const float w = wpr[c];
    a0 = fmaf(w, Wq[c * HD + t], a0);
    a1 = fmaf(w, Wq[c * HD + t + 256], a1);
  }
  MtF[fragoff(n, t, 0)]       = (f16)a0;
  MtF[fragoff(n, t + 256, 0)] = (f16)a1;
  sred[t] = wpr[t] * bq[t];
  __syncthreads();
  for (int s = 128; s > 0; s >>= 1) {
    if (t < s) sred[t] += sred[t + s];
    __syncthreads();
  }
  if (t == 0) sb[n] = sred[0];
}

// ---------------- prep: WpF = GEMM3 B fragments from Wp (k-dim = n, cols = c)
// frag element (cf, ks, lane=q4*16+l16, j) = (f16)Wp[(ks*32+q4*8+j)][cf*16+l16]
__global__ void prep_WpF(const float* __restrict__ Wp, f16* __restrict__ WpF) {
  const int bx   = blockIdx.x;        // cf*16 + ks, 0..255
  const int lane = threadIdx.x;       // 0..63
  const int cf = bx >> 4, ks = bx & 15;
  const int q4 = lane >> 4, l16 = lane & 15;
  f16x8_t v;
  #pragma unroll
  for (int j = 0; j < 8; ++j)
    v[j] = (f16)Wp[(ks * 32 + q4 * 8 + j) * CD + cf * 16 + l16];
  *(f16x8_t*)(WpF + ((bx * 64) + lane) * 8) = v;
}

// ---------------- fused main: scores = H@M^T (+sb), direct-exp softmax, Q out, P = Q@Wp
// Register model (R2/R5 measured): (512,4) -> 4 waves/EU, arch-VGPR cap 64 + AGPRs
// from unified pool. acc[2][8]=64 AGPR + ~70 VGPR fits; WRITE_SIZE is the spill tripwire.
// SWIZZLE RULE (R4): XOR applied to the FULL byte offset (XOR-last).
__global__ __launch_bounds__(NTHR, 4)
void fused_main(const float* __restrict__ Hl, const f16* __restrict__ MtF,
                const f16* __restrict__ WpF, const float* __restrict__ sb,
                float* __restrict__ outP, float* __restrict__ outQ) {
  // 64 KiB: holds H fp16 -> Q fp16 -> P fp32 (XOR-swizzled rows, stride 1024B)
  __shared__ __align__(16) char AQraw[BM * HD * 2];
  __shared__ float red[BM][4];
  __shared__ float rstat[BM];

  const int tid  = threadIdx.x;
  const int lane = tid & 63;
  const int wid  = tid >> 6;         // 0..7
  const int wr   = wid >> 2;         // 0..1 (row half: 32 rows)
  const int wc   = wid & 3;          // 0..3 (col quarter)
  const int q4   = lane >> 4;        // 0..3
  const int l16  = lane & 15;
  const long rowbase = (long)blockIdx.x * BM;

  // ---- stage H: 64 rows x 512 fp32 -> fp16 LDS (swizzled) ----
  {
    const float4* __restrict__ src = (const float4*)(Hl + rowbase * HD);
    #pragma unroll
    for (int it = 0; it < (BM * HD / 4) / NTHR; ++it) {   // 16 iters
      const int f = it * NTHR + tid;
      const float4 v = src[f];
      const int row = f >> 7;                             // 128 chunks per row
      int byteoff = row * (HD * 2) + ((f & 127) << 3);
      byteoff ^= (row & 7) << 4;
      f16x4_t h;
      h[0] = (f16)v.x; h[1] = (f16)v.y; h[2] = (f16)v.z; h[3] = (f16)v.w;
      *(f16x4_t*)(AQraw + byteoff) = h;
    }
  }
  __syncthreads();

  // ---- GEMM1: scores[64][512] = H_f16 @ M^T, fp32 acc; B from fragment buffer ----
  f32x4_t acc[2][8];
  #pragma unroll
  for (int i = 0; i < 2; ++i)
    #pragma unroll
    for (int j = 0; j < 8; ++j)
      #pragma unroll
      for (int k = 0; k < 4; ++k) acc[i][j][k] = 0.f;

  {
    const char* __restrict__ mb = (const char*)MtF + (wc * 8 * 16) * 1024 + lane * 16;
    const int arow0 = wr * 32 + l16;
    for (int ks = 0; ks < 16; ++ks) {
      f16x8_t a[2];
      #pragma unroll
      for (int mf = 0; mf < 2; ++mf) {
        const int arow = arow0 + mf * 16;
        int byteoff = arow * (HD * 2) + ks * 64 + q4 * 16;
        byteoff ^= (arow & 7) << 4;                        // XOR-last!
        a[mf] = *(const f16x8_t*)(AQraw + byteoff);
      }
      #pragma unroll
      for (int nf = 0; nf < 8; ++nf) {
        const f16x8_t b = *(const f16x8_t*)(mb + (nf * 16 + ks) * 1024);
        #pragma unroll
        for (int mf = 0; mf < 2; ++mf)
          acc[mf][nf] = __builtin_amdgcn_mfma_f32_16x16x32_f16(a[mf], b, acc[mf][nf], 0, 0, 0);
      }
    }
  }

  // ---- softmax over N=512, direct exp (no max pass: |logit| <~ 54 << 88) ----
  // thread holds rows rloc = wr*32 + mf*16 + q4*4 + r, cols wc*128 + nf*16 + l16
  float sb10[8];
  #pragma unroll
  for (int nf = 0; nf < 8; ++nf) sb10[nf] = sb[wc * 128 + nf * 16 + l16] * TINV;

  float ps[2][4] = {{0.f,0.f,0.f,0.f},{0.f,0.f,0.f,0.f}};
  #pragma unroll
  for (int mf = 0; mf < 2; ++mf)
    #pragma unroll
    for (int nf = 0; nf < 8; ++nf)
      #pragma unroll
      for (int r = 0; r < 4; ++r) {
        const float e = __expf(fmaf(acc[mf][nf][r], TINV, sb10[nf]));
        acc[mf][nf][r] = e;
        ps[mf][r] += e;
      }
  #pragma unroll
  for (int st = 8; st >= 1; st >>= 1)
    #pragma unroll
    for (int mf = 0; mf < 2; ++mf)
      #pragma unroll
      for (int r = 0; r < 4; ++r)
        ps[mf][r] += __shfl_xor(ps[mf][r], st, 64);

  if (l16 == 0) {
    #pragma unroll
    for (int mf = 0; mf < 2; ++mf)
      #pragma unroll
      for (int r = 0; r < 4; ++r)
        red[wr * 32 + mf * 16 + q4 * 4 + r][wc] = ps[mf][r];
  }
  __syncthreads();
  if (tid < BM)
    rstat[tid] = 1.0f / (red[tid][0] + red[tid][1] + red[tid][2] + red[tid][3]);
  __syncthreads();

  float rinv[2][4];
  #pragma unroll
  for (int mf = 0; mf < 2; ++mf)
    #pragma unroll
    for (int r = 0; r < 4; ++r)
      rinv[mf][r] = rstat[wr * 32 + mf * 16 + q4 * 4 + r];

  // ---- Q fp16 into AQ (H fully consumed) ----
  #pragma unroll
  for (int mf = 0; mf < 2; ++mf)
    #pragma unroll
    for (int nf = 0; nf < 8; ++nf)
      #pragma unroll
      for (int r = 0; r < 4; ++r) {
        const int rloc = wr * 32 + mf * 16 + q4 * 4 + r;
        const int col  = wc * 128 + nf * 16 + l16;
        const float q = acc[mf][nf][r] * rinv[mf][r];
        int byteoff = rloc * (ND * 2) + col * 2;
        byteoff ^= (rloc & 7) << 4;
        *(f16*)(AQraw + byteoff) = (f16)q;
      }
  __syncthreads();

  // ---- Q global store: coalesced float4 from LDS ----
  {
    #pragma unroll
    for (int it = 0; it < (BM * ND / 4) / NTHR; ++it) {   // 16 iters
      const int f = it * NTHR + tid;
      const int row = f >> 7;
      int byteoff = row * (ND * 2) + ((f & 127) << 3);
      byteoff ^= (row & 7) << 4;
      const f16x4_t qv = *(const f16x4_t*)(AQraw + byteoff);
      float4 o;
      o.x = (float)qv[0]; o.y = (float)qv[1]; o.z = (float)qv[2]; o.w = (float)qv[3];
      *(float4*)(outQ + (rowbase + row) * ND + ((f & 127) << 2)) = o;
    }
  }

  // ---- GEMM3: P[64][256] = Q_f16 @ Wp; B from fragment buffer ----
  f32x4_t acc2[2][4];
  #pragma unroll
  for (int i = 0; i < 2; ++i)
    #pragma unroll
    for (int j = 0; j < 4; ++j)
      #pragma unroll
      for (int k = 0; k < 4; ++k) acc2[i][j][k] = 0.f;

  {
    const char* __restrict__ wb = (const char*)WpF + (wc * 4 * 16) * 1024 + lane * 16;
    const int arow0 = wr * 32 + l16;
    for (int ks = 0; ks < 16; ++ks) {
      f16x8_t a[2];
      #pragma unroll
      for (int mf = 0; mf < 2; ++mf) {
        const int arow = arow0 + mf * 16;
        int byteoff = arow * (ND * 2) + ks * 64 + q4 * 16;
        byteoff ^= (arow & 7) << 4;                        // XOR-last!
        a[mf] = *(const f16x8_t*)(AQraw + byteoff);
      }
      #pragma unroll
      for (int nf = 0; nf < 4; ++nf) {
        const f16x8_t b = *(const f16x8_t*)(wb + (nf * 16 + ks) * 1024);
        #pragma unroll
        for (int mf = 0; mf < 2; ++mf)
          acc2[mf][nf] = __builtin_amdgcn_mfma_f32_16x16x32_f16(a[mf], b, acc2[mf][nf], 0, 0, 0);
      }
    }
  }
  __syncthreads();   // everyone done reading Q from AQ before overwriting with P

  // ---- P fp32 scatter into AQ, then coalesced store ----
  {
    #pragma unroll
    for (int mf = 0; mf < 2; ++mf)
      #pragma unroll
      for (int nf = 0; nf < 4; ++nf)
        #pragma unroll
        for (int r = 0; r < 4; ++r) {
          const int rloc = wr * 32 + mf * 16 + q4 * 4 + r;
          const int col  = wc * 64 + nf * 16 + l16;
          int byteoff = rloc * (CD * 4) + col * 4;
          byteoff ^= (rloc & 7) << 4;
          *(float*)(AQraw + byteoff) = acc2[mf][nf][r];
        }
    __syncthreads();
    #pragma unroll
    for (int it = 0; it < (BM * CD / 4) / NTHR; ++it) {   // 8 iters
      const int f = it * NTHR + tid;
      const int row = f >> 6;
      int byteoff = row * (CD * 4) + ((f & 63) << 4);
      byteoff ^= (row & 7) << 4;
      const float4 pv = *(const float4*)(AQraw + byteoff);
      *(float4*)(outP + (rowbase + row) * CD + ((f & 63) << 2)) = pv;
    }
  }
}

extern "C" void kernel_launch(void* const* d_in, const int* in_sizes, int n_in,
                              void* d_out, int out_size, void* d_ws, size_t ws_size,
                              hipStream_t stream) {
  const float* Hl = (const float*)d_in[0];   // (B,T,V,H)
  const float* Wp = (const float*)d_in[1];   // (N,C)
  const float* Wq = (const float*)d_in[2];   // (C,H)
  const float* bq = (const float*)d_in[3];   // (C,)

  float* outP = (float*)d_out;                         // (M, C)
  float* outQ = (float*)d_out + (long)MROWS * CD;      // (M, N)

  f16*   MtF = (f16*)d_ws;                                        // 512*512*2 = 512 KiB
  f16*   WpF = (f16*)((char*)d_ws + ND * HD * 2);                 // 256*512*2 = 256 KiB
  float* sb  = (float*)((char*)d_ws + ND * HD * 2 + CD * ND * 2); // 2 KiB

  prep_M  <<<ND, CD, 0, stream>>>(Wp, Wq, bq, MtF, sb);
  prep_WpF<<<CD, 64, 0, stream>>>(Wp, WpF);
  fused_main<<<MROWS / BM, NTHR, 0, stream>>>(Hl, MtF, WpF, sb, outP, outQ);
}